// Round 6
// baseline (165.693 us; speedup 1.0000x reference)
//
#include <hip/hip_runtime.h>
#include <hip/hip_bf16.h>
#include <math.h>

#define L_TOK 3136
#define NPATCH 32
#define VTOK 98
#define PADV 128
#define CDIM 256
#define NHEADS 8
#define HD 32

typedef __attribute__((ext_vector_type(8))) short short8;
typedef __attribute__((ext_vector_type(4))) short short4v;
typedef __attribute__((ext_vector_type(4))) float floatx4;

static __device__ __forceinline__ unsigned short bf16u(float f) {
    __hip_bfloat16 h = __float2bfloat16(f);
    return *reinterpret_cast<unsigned short*>(&h);
}
static __device__ __forceinline__ float bf16f(unsigned short u) {
    unsigned v = ((unsigned)u) << 16;
    return __uint_as_float(v);
}
static __device__ __forceinline__ void bf16pair(float v, unsigned short& hi, unsigned short& lo) {
    unsigned short h = bf16u(v);
    lo = bf16u(v - bf16f(h));
    hi = h;
}
// load 8 consecutive fp32 -> bf16 short8 fragment
static __device__ __forceinline__ short8 ldcvt(const float* p) {
    float4 a = *(const float4*)p;
    float4 b = *(const float4*)(p + 4);
    short8 r;
    r[0] = (short)bf16u(a.x); r[1] = (short)bf16u(a.y);
    r[2] = (short)bf16u(a.z); r[3] = (short)bf16u(a.w);
    r[4] = (short)bf16u(b.x); r[5] = (short)bf16u(b.y);
    r[6] = (short)bf16u(b.z); r[7] = (short)bf16u(b.w);
    return r;
}

// token l -> float offset of its contiguous 256-channel row in x / out
static __device__ __forceinline__ int token_offset(int l) {
    int pn = l / VTOK, pv = l % VTOK;
    int it = pn >> 4, ih = (pn >> 2) & 3, iw = pn & 3;
    int tt = pv / 49, r2 = pv % 49, hh = r2 / 7, ww = r2 % 7;
    return (((it * 2 + tt) * 28 + ih * 7 + hh) * 28 + iw * 7 + ww) * CDIM;
}

// ================= K1: QKV GEMM (in-reg cast) + density =================
__global__ __launch_bounds__(256) void qkv_density(const float* __restrict__ x,
                                                   const float* __restrict__ wqkv,
                                                   unsigned short* __restrict__ qb,
                                                   unsigned short* __restrict__ kb,
                                                   unsigned short* __restrict__ vt,
                                                   float* __restrict__ dens) {
    __shared__ int rowpn[64];
    __shared__ int rowpv[64];
    __shared__ float wsum[4];
    int tid = threadIdx.x;

    if (blockIdx.y == 12) {               // ---- density blocks ----
        if (blockIdx.x >= NPATCH) return;
        int n = blockIdx.x;
        int wid = tid >> 6, lane = tid & 63;
        float accn = 0.f;
        for (int v = wid; v < VTOK; v += 4) {
            int off = token_offset(n * VTOK + v);
            float4 xx = *(const float4*)(x + off + lane * 4);
            float ss = xx.x * xx.x + xx.y * xx.y + xx.z * xx.z + xx.w * xx.w;
            #pragma unroll
            for (int o = 32; o > 0; o >>= 1) ss += __shfl_down(ss, o, 64);
            if (lane == 0) accn += sqrtf(ss);
        }
        if (lane == 0) wsum[wid] = accn;
        __syncthreads();
        if (tid == 0) dens[n] = (wsum[0] + wsum[1] + wsum[2] + wsum[3]) * (1.0f / 98.0f);
        return;
    }

    // ---- GEMM blocks ----
    int m0 = blockIdx.x * 64;
    int n0 = blockIdx.y * 64;
    if (tid < 64) {
        int l = m0 + tid;
        rowpn[tid] = l / VTOK;
        rowpv[tid] = l % VTOK;
    }
    __syncthreads();
    const int wave = tid >> 6, lane = tid & 63;
    const int l16 = lane & 15, quad = lane >> 4;
    const int wm = wave & 1, wn = wave >> 1;

    int r0 = m0 + wm * 32 + l16;
    int aoff0 = token_offset(r0);
    int aoff1 = token_offset(r0 + 16);
    int boff0 = (n0 + wn * 32 + l16) * CDIM;
    int boff1 = boff0 + 16 * CDIM;

    const floatx4 zerov = {0.f, 0.f, 0.f, 0.f};
    floatx4 acc[2][2] = {{zerov, zerov}, {zerov, zerov}};
    #pragma unroll
    for (int k0 = 0; k0 < CDIM; k0 += 32) {
        int kk = k0 + quad * 8;
        short8 a0 = ldcvt(x + aoff0 + kk);
        short8 a1 = ldcvt(x + aoff1 + kk);
        short8 b0 = ldcvt(wqkv + boff0 + kk);
        short8 b1 = ldcvt(wqkv + boff1 + kk);
        acc[0][0] = __builtin_amdgcn_mfma_f32_16x16x32_bf16(a0, b0, acc[0][0], 0, 0, 0);
        acc[0][1] = __builtin_amdgcn_mfma_f32_16x16x32_bf16(a0, b1, acc[0][1], 0, 0, 0);
        acc[1][0] = __builtin_amdgcn_mfma_f32_16x16x32_bf16(a1, b0, acc[1][0], 0, 0, 0);
        acc[1][1] = __builtin_amdgcn_mfma_f32_16x16x32_bf16(a1, b1, acc[1][1], 0, 0, 0);
    }

    const float sc = 0.17677669529663689f;  // 32^-0.5 folded into Q
    #pragma unroll
    for (int mt = 0; mt < 2; ++mt) {
        #pragma unroll
        for (int nt = 0; nt < 2; ++nt) {
            int col = n0 + wn * 32 + nt * 16 + l16;
            #pragma unroll
            for (int r = 0; r < 4; ++r) {
                int mrow = wm * 32 + mt * 16 + quad * 4 + r;
                int pn = rowpn[mrow], vv = rowpv[mrow];
                float val = acc[mt][nt][r];
                if (col < 256) {
                    qb[(size_t)(pn * PADV + vv) * CDIM + col] = bf16u(val * sc);
                } else if (col < 512) {
                    kb[(size_t)(pn * PADV + vv) * CDIM + (col - 256)] = bf16u(val);
                } else {
                    vt[(size_t)pn * (CDIM * PADV) + (col - 512) * PADV + vv] = bf16u(val);
                }
            }
        }
    }
}

// ================= K2: MFMA flash attention (S^T C-layout == PV A-layout) =================
__global__ __launch_bounds__(512) void attn_mfma(const unsigned short* __restrict__ qb,
                                                 const unsigned short* __restrict__ kb,
                                                 const unsigned short* __restrict__ vt,
                                                 const float* __restrict__ dens,
                                                 unsigned short* __restrict__ ohi,
                                                 unsigned short* __restrict__ olo) {
    const int i = blockIdx.x, h = blockIdx.y;
    const int tid = threadIdx.x;
    const int wave = tid >> 6, lane = tid & 63;
    const int l16 = lane & 15, quad = lane >> 4;
    if (wave >= 7) return;                // 7 q-tiles of 16 rows cover 112 >= 98

    // ---- mask computed redundantly per wave (no barriers, no LDS) ----
    unsigned maskbits;
    {
        int j = lane & 31;
        float dj = dens[j];
        float m = dj;
        #pragma unroll
        for (int o = 16; o > 0; o >>= 1) m = fmaxf(m, __shfl_xor(m, o, 64));
        float inv = 1.0f / (m + 1e-8f);
        float dni = dens[i] * inv, dnj = dj * inv;
        int it_i = i >> 4, ih_i = (i >> 2) & 3, iw_i = i & 3;
        int it_j = j >> 4, ih_j = (j >> 2) & 3, iw_j = j & 3;
        float t_dist = fabsf((float)(2 * (it_i - it_j))) * 2.0f;
        float h_dist = fabsf((float)(7 * (ih_i - ih_j))) * 7.0f;
        float w_dist = fabsf((float)(7 * (iw_i - iw_j))) * 7.0f;
        float spatial = sqrtf(h_dist * h_dist + w_dist * w_dist);
        float prox = expf(-spatial / 32.0f) * expf(-t_dist / 2.0f);
        float val = (j == i) ? -1e30f : (sqrtf(dni * dnj + 1e-8f) + prox);
        unsigned picked = 0;
        #pragma unroll
        for (int t = 0; t < 4; ++t) {
            float best = val;
            #pragma unroll
            for (int o = 16; o > 0; o >>= 1) best = fmaxf(best, __shfl_xor(best, o, 64));
            unsigned long long b = __ballot(val == best);
            int bj = (__ffsll((long long)b) - 1) & 31;  // lowest index wins ties (lax.top_k stable)
            picked |= 1u << bj;
            if ((lane & 31) == bj) val = -1e30f;
        }
        int delta = j - i;
        bool inwin = false;
        #pragma unroll
        for (int dt = -1; dt <= 1; ++dt)
            #pragma unroll
            for (int dh = -1; dh <= 1; ++dh)
                #pragma unroll
                for (int dw = -1; dw <= 1; ++dw)
                    inwin = inwin || (delta == dt * 25 + dh * 5 + dw);
        unsigned wmask = (unsigned)(__ballot(inwin) & 0xFFFFFFFFull);
        maskbits = wmask | picked;
    }

    const int tile = wave;                // q rows [tile*16, tile*16+16)
    // B-operand for QK^T (S^T): Q[n=q=l16][k=ch]
    short8 Qf = *(const short8*)(qb + (size_t)(i * PADV + tile * 16 + l16) * CDIM + h * HD + quad * 8);

    const floatx4 zerov = {0.f, 0.f, 0.f, 0.f};
    floatx4 O0 = zerov, O1 = zerov;       // C-layout: col=l16=ch(half), row=quad*4+r=q
    float lsum = 0.f;

    unsigned bits = maskbits;
    while (bits) {
        int j = __ffs(bits) - 1;
        bits &= bits - 1;
        const unsigned short* kbase = kb + (size_t)(j * PADV) * CDIM + h * HD;
        const unsigned short* vbase = vt + (size_t)j * (CDIM * PADV) + (h * HD) * PADV;
        #pragma unroll
        for (int c = 0; c < 7; ++c) {     // 7 chunks x 16 keys = 112 padded keys
            // S^T = K·Q^T : lane(l16=q, quad) holds keys quad*4+r of this chunk
            short8 Kf = *(const short8*)(kbase + (c * 16 + l16) * CDIM + quad * 8);
            floatx4 S = __builtin_amdgcn_mfma_f32_16x16x32_bf16(Kf, Qf, zerov, 0, 0, 0);
            float p[4];
            #pragma unroll
            for (int r = 0; r < 4; ++r) {
                bool valid = (c < 6) || (quad == 0 && r < 2);   // keys >= 98 masked
                p[r] = valid ? __expf(S[r]) : 0.f;
            }
            lsum += (p[0] + p[1]) + (p[2] + p[3]);
            // S^T C-layout IS the 16x16x16 A-frag layout: A[m=q=l16][k=key=quad*4+j]
            short4v Pf;
            Pf[0] = (short)bf16u(p[0]); Pf[1] = (short)bf16u(p[1]);
            Pf[2] = (short)bf16u(p[2]); Pf[3] = (short)bf16u(p[3]);
            // B[n=ch=l16][k=key=quad*4+j] from vt
            short4v Vf0 = *(const short4v*)(vbase + l16 * PADV + c * 16 + quad * 4);
            short4v Vf1 = *(const short4v*)(vbase + (16 + l16) * PADV + c * 16 + quad * 4);
            O0 = __builtin_amdgcn_mfma_f32_16x16x16bf16_1k(Pf, Vf0, O0, 0, 0, 0);
            O1 = __builtin_amdgcn_mfma_f32_16x16x16bf16_1k(Pf, Vf1, O1, 0, 0, 0);
        }
    }

    // ---- epilogue: reduce l across quads, normalize, hi/lo split store ----
    lsum += __shfl_xor(lsum, 16, 64);
    lsum += __shfl_xor(lsum, 32, 64);     // lane with l16=q holds full l (all quads)
    #pragma unroll
    for (int r = 0; r < 4; ++r) {
        int q = tile * 16 + quad * 4 + r;
        float lv = __shfl(lsum, quad * 4 + r);   // read from lane (quad*4+r) -> l for row q
        if (q < VTOK) {
            float invl = 1.0f / lv;
            size_t base = (size_t)(i * VTOK + q) * CDIM + h * HD;
            float v0 = O0[r] * invl, v1 = O1[r] * invl;
            unsigned short h0, g0, h1, g1;
            bf16pair(v0, h0, g0);
            bf16pair(v1, h1, g1);
            ohi[base + l16] = h0;       olo[base + l16] = g0;
            ohi[base + 16 + l16] = h1;  olo[base + 16 + l16] = g1;
        }
    }
}

// ================= K3: proj GEMM (split-precision, 64x32 tiles) =================
__global__ __launch_bounds__(256) void proj_gemm(const unsigned short* __restrict__ ohi,
                                                 const unsigned short* __restrict__ olo,
                                                 const float* __restrict__ wproj,
                                                 const float* __restrict__ bp,
                                                 float* __restrict__ out) {
    __shared__ int rowoff[64];
    __shared__ __align__(16) unsigned short Bh[32][264];
    __shared__ __align__(16) unsigned short Bl[32][264];
    int tid = threadIdx.x;
    int m0 = blockIdx.x * 64;
    int n0 = blockIdx.y * 32;
    if (tid < 64) rowoff[tid] = token_offset(m0 + tid);
    // stage w_proj tile (32 rows) as hi/lo bf16 in LDS
    #pragma unroll
    for (int rep = 0; rep < 8; ++rep) {
        int flat = rep * 256 + tid;       // 2048 float4 groups = 32 rows x 64 groups
        int row = flat >> 6;
        int c4 = (flat & 63) * 4;
        float4 v = *(const float4*)(wproj + (size_t)(n0 + row) * CDIM + c4);
        ushort4 uh, ul;
        bf16pair(v.x, uh.x, ul.x); bf16pair(v.y, uh.y, ul.y);
        bf16pair(v.z, uh.z, ul.z); bf16pair(v.w, uh.w, ul.w);
        *(ushort4*)(&Bh[row][c4]) = uh;
        *(ushort4*)(&Bl[row][c4]) = ul;
    }
    __syncthreads();

    const int wave = tid >> 6, lane = tid & 63;   // wave = m-subtile
    const int l16 = lane & 15, quad = lane >> 4;

    size_t arow = (size_t)(m0 + wave * 16 + l16) * CDIM + quad * 8;

    const floatx4 zerov = {0.f, 0.f, 0.f, 0.f};
    floatx4 acc[2] = {zerov, zerov};
    #pragma unroll 2
    for (int k0 = 0; k0 < CDIM; k0 += 32) {
        int kk = k0 + quad * 8;
        short8 ah = *(const short8*)(ohi + arow + k0);
        short8 al = *(const short8*)(olo + arow + k0);
        short8 bh0 = *(const short8*)(&Bh[l16][kk]);
        short8 bh1 = *(const short8*)(&Bh[16 + l16][kk]);
        short8 bl0 = *(const short8*)(&Bl[l16][kk]);
        short8 bl1 = *(const short8*)(&Bl[16 + l16][kk]);
        acc[0] = __builtin_amdgcn_mfma_f32_16x16x32_bf16(al, bh0, acc[0], 0, 0, 0);
        acc[0] = __builtin_amdgcn_mfma_f32_16x16x32_bf16(ah, bl0, acc[0], 0, 0, 0);
        acc[0] = __builtin_amdgcn_mfma_f32_16x16x32_bf16(ah, bh0, acc[0], 0, 0, 0);
        acc[1] = __builtin_amdgcn_mfma_f32_16x16x32_bf16(al, bh1, acc[1], 0, 0, 0);
        acc[1] = __builtin_amdgcn_mfma_f32_16x16x32_bf16(ah, bl1, acc[1], 0, 0, 0);
        acc[1] = __builtin_amdgcn_mfma_f32_16x16x32_bf16(ah, bh1, acc[1], 0, 0, 0);
    }

    #pragma unroll
    for (int nt = 0; nt < 2; ++nt) {
        int col = n0 + nt * 16 + l16;
        float bias = bp[col];
        #pragma unroll
        for (int r = 0; r < 4; ++r) {
            int mrow = wave * 16 + quad * 4 + r;
            out[rowoff[mrow] + col] = acc[nt][r] + bias;
        }
    }
}

extern "C" void kernel_launch(void* const* d_in, const int* in_sizes, int n_in,
                              void* d_out, int out_size, void* d_ws, size_t ws_size,
                              hipStream_t stream) {
    const float* x      = (const float*)d_in[0];
    const float* w_qkv  = (const float*)d_in[1];
    const float* w_proj = (const float*)d_in[2];
    const float* b_proj = (const float*)d_in[3];
    float* out = (float*)d_out;

    unsigned short* qb  = (unsigned short*)d_ws;                 // 32*128*256
    unsigned short* kb  = qb  + (size_t)NPATCH * PADV * CDIM;
    unsigned short* vt  = kb  + (size_t)NPATCH * PADV * CDIM;
    unsigned short* ohi = vt  + (size_t)NPATCH * PADV * CDIM;    // 3136*256
    unsigned short* olo = ohi + (size_t)L_TOK * CDIM;
    float* dens = (float*)(olo + (size_t)L_TOK * CDIM);          // 32

    qkv_density<<<dim3(49, 13), 256, 0, stream>>>(x, w_qkv, qb, kb, vt, dens);
    attn_mfma<<<dim3(NPATCH, NHEADS), 512, 0, stream>>>(qb, kb, vt, dens, ohi, olo);
    proj_gemm<<<dim3(49, 8), 256, 0, stream>>>(ohi, olo, w_proj, b_proj, out);
}

// Round 7
// 119.821 us; speedup vs baseline: 1.3828x; 1.3828x over previous
//
#include <hip/hip_runtime.h>
#include <hip/hip_bf16.h>
#include <math.h>

#define L_TOK 3136
#define NPATCH 32
#define VTOK 98
#define PADV 128
#define CDIM 256
#define NHEADS 8
#define HD 32

typedef __attribute__((ext_vector_type(8))) short short8;
typedef __attribute__((ext_vector_type(4))) short short4v;
typedef __attribute__((ext_vector_type(4))) float floatx4;

union PU { unsigned u[2]; short4v s; };

static __device__ __forceinline__ unsigned short bf16u(float f) {
    __hip_bfloat16 h = __float2bfloat16(f);
    return *reinterpret_cast<unsigned short*>(&h);
}
static __device__ __forceinline__ float bf16f(unsigned short u) {
    unsigned v = ((unsigned)u) << 16;
    return __uint_as_float(v);
}
static __device__ __forceinline__ void bf16pair(float v, unsigned short& hi, unsigned short& lo) {
    unsigned short h = bf16u(v);
    lo = bf16u(v - bf16f(h));
    hi = h;
}
// load 8 consecutive fp32 -> bf16 short8 fragment
static __device__ __forceinline__ short8 ldcvt(const float* p) {
    float4 a = *(const float4*)p;
    float4 b = *(const float4*)(p + 4);
    short8 r;
    r[0] = (short)bf16u(a.x); r[1] = (short)bf16u(a.y);
    r[2] = (short)bf16u(a.z); r[3] = (short)bf16u(a.w);
    r[4] = (short)bf16u(b.x); r[5] = (short)bf16u(b.y);
    r[6] = (short)bf16u(b.z); r[7] = (short)bf16u(b.w);
    return r;
}

// token l -> float offset of its contiguous 256-channel row in x / out
static __device__ __forceinline__ int token_offset(int l) {
    int pn = l / VTOK, pv = l % VTOK;
    int it = pn >> 4, ih = (pn >> 2) & 3, iw = pn & 3;
    int tt = pv / 49, r2 = pv % 49, hh = r2 / 7, ww = r2 % 7;
    return (((it * 2 + tt) * 28 + ih * 7 + hh) * 28 + iw * 7 + ww) * CDIM;
}

// ================= K1: QKV GEMM (in-reg cast) + density =================
__global__ __launch_bounds__(256) void qkv_density(const float* __restrict__ x,
                                                   const float* __restrict__ wqkv,
                                                   unsigned short* __restrict__ qb,
                                                   unsigned short* __restrict__ kb,
                                                   unsigned short* __restrict__ vt,
                                                   float* __restrict__ dens) {
    __shared__ int rowpn[64];
    __shared__ int rowpv[64];
    __shared__ float wsum[4];
    int tid = threadIdx.x;

    if (blockIdx.y == 12) {               // ---- density blocks ----
        if (blockIdx.x >= NPATCH) return;
        int n = blockIdx.x;
        int wid = tid >> 6, lane = tid & 63;
        float accn = 0.f;
        for (int v = wid; v < VTOK; v += 4) {
            int off = token_offset(n * VTOK + v);
            float4 xx = *(const float4*)(x + off + lane * 4);
            float ss = xx.x * xx.x + xx.y * xx.y + xx.z * xx.z + xx.w * xx.w;
            #pragma unroll
            for (int o = 32; o > 0; o >>= 1) ss += __shfl_down(ss, o, 64);
            if (lane == 0) accn += sqrtf(ss);
        }
        if (lane == 0) wsum[wid] = accn;
        __syncthreads();
        if (tid == 0) dens[n] = (wsum[0] + wsum[1] + wsum[2] + wsum[3]) * (1.0f / 98.0f);
        return;
    }

    // ---- GEMM blocks ----
    int m0 = blockIdx.x * 64;
    int n0 = blockIdx.y * 64;
    if (tid < 64) {
        int l = m0 + tid;
        rowpn[tid] = l / VTOK;
        rowpv[tid] = l % VTOK;
    }
    __syncthreads();
    const int wave = tid >> 6, lane = tid & 63;
    const int l16 = lane & 15, quad = lane >> 4;
    const int wm = wave & 1, wn = wave >> 1;

    int r0 = m0 + wm * 32 + l16;
    int aoff0 = token_offset(r0);
    int aoff1 = token_offset(r0 + 16);
    int boff0 = (n0 + wn * 32 + l16) * CDIM;
    int boff1 = boff0 + 16 * CDIM;

    const floatx4 zerov = {0.f, 0.f, 0.f, 0.f};
    floatx4 acc[2][2] = {{zerov, zerov}, {zerov, zerov}};
    #pragma unroll
    for (int k0 = 0; k0 < CDIM; k0 += 32) {
        int kk = k0 + quad * 8;
        short8 a0 = ldcvt(x + aoff0 + kk);
        short8 a1 = ldcvt(x + aoff1 + kk);
        short8 b0 = ldcvt(wqkv + boff0 + kk);
        short8 b1 = ldcvt(wqkv + boff1 + kk);
        acc[0][0] = __builtin_amdgcn_mfma_f32_16x16x32_bf16(a0, b0, acc[0][0], 0, 0, 0);
        acc[0][1] = __builtin_amdgcn_mfma_f32_16x16x32_bf16(a0, b1, acc[0][1], 0, 0, 0);
        acc[1][0] = __builtin_amdgcn_mfma_f32_16x16x32_bf16(a1, b0, acc[1][0], 0, 0, 0);
        acc[1][1] = __builtin_amdgcn_mfma_f32_16x16x32_bf16(a1, b1, acc[1][1], 0, 0, 0);
    }

    const float sc = 0.17677669529663689f;  // 32^-0.5 folded into Q
    #pragma unroll
    for (int mt = 0; mt < 2; ++mt) {
        #pragma unroll
        for (int nt = 0; nt < 2; ++nt) {
            int col = n0 + wn * 32 + nt * 16 + l16;
            #pragma unroll
            for (int r = 0; r < 4; ++r) {
                int mrow = wm * 32 + mt * 16 + quad * 4 + r;
                int pn = rowpn[mrow], vv = rowpv[mrow];
                float val = acc[mt][nt][r];
                if (col < 256) {
                    qb[(size_t)(pn * PADV + vv) * CDIM + col] = bf16u(val * sc);
                } else if (col < 512) {
                    kb[(size_t)(pn * PADV + vv) * CDIM + (col - 256)] = bf16u(val);
                } else {
                    vt[(size_t)pn * (CDIM * PADV) + (col - 512) * PADV + vv] = bf16u(val);
                }
            }
        }
    }
}

// ================= K2: MFMA flash attention (7-tile ILP per wave, j-split 4, LDS merge) =====
__global__ __launch_bounds__(256) void attn_mfma(const unsigned short* __restrict__ qb,
                                                 const unsigned short* __restrict__ kb,
                                                 const unsigned short* __restrict__ vt,
                                                 const float* __restrict__ dens,
                                                 unsigned short* __restrict__ ohi,
                                                 unsigned short* __restrict__ olo) {
    __shared__ floatx4 ldsO[4][7][2][64];   // 57344 B
    __shared__ float   ldsL[4][7][64];      //  7168 B
    const int i = blockIdx.x, h = blockIdx.y;
    const int tid = threadIdx.x;
    const int wave = tid >> 6, lane = tid & 63;
    const int l16 = lane & 15, quad = lane >> 4;

    // ---- mask computed redundantly per wave (no barrier before main loop) ----
    unsigned maskbits;
    {
        int j = lane & 31;
        float dj = dens[j];
        float m = dj;
        #pragma unroll
        for (int o = 16; o > 0; o >>= 1) m = fmaxf(m, __shfl_xor(m, o, 64));
        float inv = 1.0f / (m + 1e-8f);
        float dni = dens[i] * inv, dnj = dj * inv;
        int it_i = i >> 4, ih_i = (i >> 2) & 3, iw_i = i & 3;
        int it_j = j >> 4, ih_j = (j >> 2) & 3, iw_j = j & 3;
        float t_dist = fabsf((float)(2 * (it_i - it_j))) * 2.0f;
        float h_dist = fabsf((float)(7 * (ih_i - ih_j))) * 7.0f;
        float w_dist = fabsf((float)(7 * (iw_i - iw_j))) * 7.0f;
        float spatial = sqrtf(h_dist * h_dist + w_dist * w_dist);
        float prox = expf(-spatial / 32.0f) * expf(-t_dist / 2.0f);
        float val = (j == i) ? -1e30f : (sqrtf(dni * dnj + 1e-8f) + prox);
        unsigned picked = 0;
        #pragma unroll
        for (int t = 0; t < 4; ++t) {
            float best = val;
            #pragma unroll
            for (int o = 16; o > 0; o >>= 1) best = fmaxf(best, __shfl_xor(best, o, 64));
            unsigned long long b = __ballot(val == best);
            int bj = (__ffsll((long long)b) - 1) & 31;  // lowest index wins ties (lax.top_k stable)
            picked |= 1u << bj;
            if ((lane & 31) == bj) val = -1e30f;
        }
        int delta = j - i;
        bool inwin = false;
        #pragma unroll
        for (int dt = -1; dt <= 1; ++dt)
            #pragma unroll
            for (int dh = -1; dh <= 1; ++dh)
                #pragma unroll
                for (int dw = -1; dw <= 1; ++dw)
                    inwin = inwin || (delta == dt * 25 + dh * 5 + dw);
        unsigned wmask = (unsigned)(__ballot(inwin) & 0xFFFFFFFFull);
        maskbits = wmask | picked;
    }

    // ---- all 7 q-tiles live in registers: 7 independent chains per wave ----
    short8 Qf[7];
    #pragma unroll
    for (int t = 0; t < 7; ++t)
        Qf[t] = *(const short8*)(qb + (size_t)(i * PADV + t * 16 + l16) * CDIM + h * HD + quad * 8);

    const floatx4 zerov = {0.f, 0.f, 0.f, 0.f};
    floatx4 O[7][2];
    float lsum[7];
    #pragma unroll
    for (int t = 0; t < 7; ++t) { O[t][0] = zerov; O[t][1] = zerov; lsum[t] = 0.f; }

    // this wave takes every 4th set bit (rank % 4 == wave)
    unsigned bits = maskbits;
    int rank = 0;
    while (bits) {
        int j = __ffs(bits) - 1;
        bits &= bits - 1;
        if ((rank++ & 3) != wave) continue;
        const unsigned short* kbase = kb + (size_t)(j * PADV) * CDIM + h * HD;
        const unsigned short* vbase = vt + (size_t)j * (CDIM * PADV) + (h * HD) * PADV;
        #pragma unroll
        for (int c = 0; c < 7; ++c) {     // 7 chunks x 16 keys; one K/V load feeds 7 tiles
            short8 Kf = *(const short8*)(kbase + (c * 16 + l16) * CDIM + quad * 8);
            short4v Vf0 = *(const short4v*)(vbase + l16 * PADV + c * 16 + quad * 4);
            short4v Vf1 = *(const short4v*)(vbase + (16 + l16) * PADV + c * 16 + quad * 4);
            #pragma unroll
            for (int t = 0; t < 7; ++t) {
                // S^T = K·Q^T : lane(l16=q, quad) holds keys quad*4+r  == 16x16x16 A-frag layout
                floatx4 S = __builtin_amdgcn_mfma_f32_16x16x32_bf16(Kf, Qf[t], zerov, 0, 0, 0);
                unsigned up[4];
                #pragma unroll
                for (int r = 0; r < 4; ++r) {
                    float e = __expf(S[r]);
                    if (c == 6 && !(quad == 0 && r < 2)) e = 0.f;   // keys >= 98 masked
                    unsigned ue = __float_as_uint(e) & 0xFFFF0000u; // truncate to bf16
                    up[r] = ue;
                    lsum[t] += __uint_as_float(ue);                 // l sums SAME truncated p -> bias cancels
                }
                PU pu;
                pu.u[0] = __builtin_amdgcn_perm(up[1], up[0], 0x07060302u);
                pu.u[1] = __builtin_amdgcn_perm(up[3], up[2], 0x07060302u);
                O[t][0] = __builtin_amdgcn_mfma_f32_16x16x16bf16_1k(pu.s, Vf0, O[t][0], 0, 0, 0);
                O[t][1] = __builtin_amdgcn_mfma_f32_16x16x16bf16_1k(pu.s, Vf1, O[t][1], 0, 0, 0);
            }
        }
    }

    // ---- merge partials across the 4 waves via LDS ----
    #pragma unroll
    for (int t = 0; t < 7; ++t) {
        ldsO[wave][t][0][lane] = O[t][0];
        ldsO[wave][t][1][lane] = O[t][1];
        ldsL[wave][t][lane] = lsum[t];
    }
    __syncthreads();
    for (int u = wave; u < 14; u += 4) {
        int t = u >> 1, half = u & 1;
        floatx4 Os = ldsO[0][t][half][lane] + ldsO[1][t][half][lane]
                   + ldsO[2][t][half][lane] + ldsO[3][t][half][lane];
        float Ls = ldsL[0][t][lane] + ldsL[1][t][lane] + ldsL[2][t][lane] + ldsL[3][t][lane];
        Ls += __shfl_xor(Ls, 16, 64);
        Ls += __shfl_xor(Ls, 32, 64);     // lanes with l16=q hold full row-sum
        #pragma unroll
        for (int r = 0; r < 4; ++r) {
            int q = t * 16 + quad * 4 + r;
            float lv = __shfl(Ls, quad * 4 + r);
            if (q < VTOK) {
                float invl = 1.0f / lv;
                float v = Os[r] * invl;
                unsigned short hi, lo;
                bf16pair(v, hi, lo);
                size_t base = (size_t)(i * VTOK + q) * CDIM + h * HD + half * 16;
                ohi[base + l16] = hi;
                olo[base + l16] = lo;
            }
        }
    }
}

// ================= K3: proj GEMM (split-precision, 64x32 tiles) =================
__global__ __launch_bounds__(256) void proj_gemm(const unsigned short* __restrict__ ohi,
                                                 const unsigned short* __restrict__ olo,
                                                 const float* __restrict__ wproj,
                                                 const float* __restrict__ bp,
                                                 float* __restrict__ out) {
    __shared__ int rowoff[64];
    __shared__ __align__(16) unsigned short Bh[32][264];
    __shared__ __align__(16) unsigned short Bl[32][264];
    int tid = threadIdx.x;
    int m0 = blockIdx.x * 64;
    int n0 = blockIdx.y * 32;
    if (tid < 64) rowoff[tid] = token_offset(m0 + tid);
    // stage w_proj tile (32 rows) as hi/lo bf16 in LDS
    #pragma unroll
    for (int rep = 0; rep < 8; ++rep) {
        int flat = rep * 256 + tid;       // 2048 float4 groups = 32 rows x 64 groups
        int row = flat >> 6;
        int c4 = (flat & 63) * 4;
        float4 v = *(const float4*)(wproj + (size_t)(n0 + row) * CDIM + c4);
        ushort4 uh, ul;
        bf16pair(v.x, uh.x, ul.x); bf16pair(v.y, uh.y, ul.y);
        bf16pair(v.z, uh.z, ul.z); bf16pair(v.w, uh.w, ul.w);
        *(ushort4*)(&Bh[row][c4]) = uh;
        *(ushort4*)(&Bl[row][c4]) = ul;
    }
    __syncthreads();

    const int wave = tid >> 6, lane = tid & 63;   // wave = m-subtile
    const int l16 = lane & 15, quad = lane >> 4;

    size_t arow = (size_t)(m0 + wave * 16 + l16) * CDIM + quad * 8;

    const floatx4 zerov = {0.f, 0.f, 0.f, 0.f};
    floatx4 acc[2] = {zerov, zerov};
    #pragma unroll 2
    for (int k0 = 0; k0 < CDIM; k0 += 32) {
        int kk = k0 + quad * 8;
        short8 ah = *(const short8*)(ohi + arow + k0);
        short8 al = *(const short8*)(olo + arow + k0);
        short8 bh0 = *(const short8*)(&Bh[l16][kk]);
        short8 bh1 = *(const short8*)(&Bh[16 + l16][kk]);
        short8 bl0 = *(const short8*)(&Bl[l16][kk]);
        short8 bl1 = *(const short8*)(&Bl[16 + l16][kk]);
        acc[0] = __builtin_amdgcn_mfma_f32_16x16x32_bf16(al, bh0, acc[0], 0, 0, 0);
        acc[0] = __builtin_amdgcn_mfma_f32_16x16x32_bf16(ah, bl0, acc[0], 0, 0, 0);
        acc[0] = __builtin_amdgcn_mfma_f32_16x16x32_bf16(ah, bh0, acc[0], 0, 0, 0);
        acc[1] = __builtin_amdgcn_mfma_f32_16x16x32_bf16(al, bh1, acc[1], 0, 0, 0);
        acc[1] = __builtin_amdgcn_mfma_f32_16x16x32_bf16(ah, bl1, acc[1], 0, 0, 0);
        acc[1] = __builtin_amdgcn_mfma_f32_16x16x32_bf16(ah, bh1, acc[1], 0, 0, 0);
    }

    #pragma unroll
    for (int nt = 0; nt < 2; ++nt) {
        int col = n0 + nt * 16 + l16;
        float bias = bp[col];
        #pragma unroll
        for (int r = 0; r < 4; ++r) {
            int mrow = wave * 16 + quad * 4 + r;
            out[rowoff[mrow] + col] = acc[nt][r] + bias;
        }
    }
}

extern "C" void kernel_launch(void* const* d_in, const int* in_sizes, int n_in,
                              void* d_out, int out_size, void* d_ws, size_t ws_size,
                              hipStream_t stream) {
    const float* x      = (const float*)d_in[0];
    const float* w_qkv  = (const float*)d_in[1];
    const float* w_proj = (const float*)d_in[2];
    const float* b_proj = (const float*)d_in[3];
    float* out = (float*)d_out;

    unsigned short* qb  = (unsigned short*)d_ws;                 // 32*128*256
    unsigned short* kb  = qb  + (size_t)NPATCH * PADV * CDIM;
    unsigned short* vt  = kb  + (size_t)NPATCH * PADV * CDIM;
    unsigned short* ohi = vt  + (size_t)NPATCH * PADV * CDIM;    // 3136*256
    unsigned short* olo = ohi + (size_t)L_TOK * CDIM;
    float* dens = (float*)(olo + (size_t)L_TOK * CDIM);          // 32

    qkv_density<<<dim3(49, 13), 256, 0, stream>>>(x, w_qkv, qb, kb, vt, dens);
    attn_mfma<<<dim3(NPATCH, NHEADS), 256, 0, stream>>>(qb, kb, vt, dens, ohi, olo);
    proj_gemm<<<dim3(49, 8), 256, 0, stream>>>(ohi, olo, w_proj, b_proj, out);
}